// Round 17
// baseline (109.719 us; speedup 1.0000x reference)
//
#include <hip/hip_runtime.h>

#define IMG    512
#define WT     64          // w-tile (lanes)
#define HT     64          // h per strip
#define NSTRIP (IMG / HT)  // 8 strips -> one WG integrates the FULL line
#define NT     512         // 8 waves
#define HC     8           // h-chunks per strip (one per wave)
#define HPER   (HT / HC)   // 8 samples per thread per strip
#define ROWS   96          // staged rows (worst-case strip span ~95)
#define PITCH_A 95         // c*s >= 0  (95 % 32 == 31: bank ~ jx - jy, lane-step |c|+s)
#define PITCH_B 97         // c*s <  0  (97 % 32 ==  1: bank ~ jx + jy, lane-step |c|+s)
#define BUF_FLOATS (ROWS * PITCH_B + 8)   // 9320 floats = 37.3 KB -> 4 WG/CU

// Direct global->LDS DMA: wave-uniform LDS base, HW adds lane*4.
__device__ __forceinline__ void gload_lds4(const float* g, float* l) {
    __builtin_amdgcn_global_load_lds((const __attribute__((address_space(1))) void*)g,
                                     (__attribute__((address_space(3))) void*)l, 4, 0, 0);
}

// single-instruction fractional part
__device__ __forceinline__ float vfract(float x) {
    float r;
    asm("v_fract_f32 %0, %1" : "=v"(r) : "v"(x));
    return r;
}

template<int PITCH>
__device__ __forceinline__ float lerp4(const float* __restrict__ tile,
                                       float fx, float fy) {
    int jx = (int)fx;                  // fx,fy >= 1: trunc == floor
    int jy = (int)fy;
    const float* __restrict__ p = tile + (__mul24(jy, PITCH) + jx);
    float v00 = p[0];
    float v01 = p[1];                  // ds_read2_b32 (0,1)
    float v10 = p[PITCH];
    float v11 = p[PITCH + 1];          // ds_read2_b32 (PITCH,PITCH+1)
    float wx1 = vfract(fx);
    float wy1 = vfract(fy);
    float lx0 = fmaf(wx1, v01 - v00, v00);
    float lx1 = fmaf(wx1, v11 - v10, v10);
    return fmaf(wy1, lx1 - lx0, lx0);
}

// Full line integral for one (n, w-tile, angle): loop h-strips, staging each
// strip's rotated bbox into LDS (zero-embedded -> implicit zero padding).
template<int PITCH>
__device__ __forceinline__ void radon_body(
    const float* __restrict__ img, float* __restrict__ tile,
    float* __restrict__ out, float s, float c,
    int n, int a, int w0, int A)
{
    int lane = threadIdx.x & 63;
    int wv   = threadIdx.x >> 6;

    // ix(w,h) = c*u + s*t + 255.5, iy = -s*u + c*t + 255.5; u,t = coord-255.5
    float u   = (float)(w0 + lane) - 255.5f;
    float uc  = (float)w0 + (31.5f - 255.5f);
    float ex  = (fabsf(c) + s) * 31.5f;          // half-extent (square strip)
    float ixc = fmaf(c, uc, fmaf(s, (31.5f - 255.5f), 255.5f));
    float iyc = fmaf(-s, uc, fmaf(c, (31.5f - 255.5f), 255.5f));

    bool has_staged = false;                     // WG-uniform
    float acc = 0.0f;
    for (int st = 0; st < NSTRIP; ++st) {
        int xmin = (int)floorf(ixc - ex) - 1;
        int ymin = (int)floorf(iyc - ex) - 1;
        int nxn  = min((int)floorf(ixc + ex) - xmin + 3, PITCH);  // 66..95
        int nyn  = min((int)floorf(iyc + ex) - ymin + 3, ROWS);
        ixc += s * (float)HT;                    // advance strip center now;
        iyc += c * (float)HT;                    // bbox already captured

        // fully-outside strip: every tap lies in the bbox, bbox misses the
        // image -> all reference weights are 0 -> contributes exactly 0.
        // WG-uniform; skip staging, barriers, and sampling.
        int gx0 = max(xmin, 0), gx1 = min(xmin + nxn, IMG);
        int gy0 = max(ymin, 0), gy1 = min(ymin + nyn, IMG);
        if (gx0 >= gx1 || gy0 >= gy1) continue;

        if (has_staged) __syncthreads();         // prev strip's reads done
        has_staged = true;

        bool border = (xmin < 0) | (ymin < 0) | (xmin + nxn > IMG) | (ymin + nyn > IMG);
        if (!border) {
            // interior: pure DMA, pointer-marched rows, hoisted predicate
            bool has2 = (64 + lane) < nxn;       // loop-invariant per strip
            const float* __restrict__ srcp = img + (size_t)(ymin + wv) * IMG + (xmin + lane);
            int doff = __mul24(wv, PITCH);
            for (int yy = wv; yy < nyn; yy += HC) {
                float* dst = tile + doff;
                gload_lds4(srcp, dst);                       // nxn >= 66
                if (has2) gload_lds4(srcp + 64, dst + 64);
                srcp += HC * IMG;
                doff += HC * PITCH;
            }
        } else {
            // border: zero-prefill ALL rows, then BARRIER, then DMA.
            // The barrier is required: zero-fill rows are owned by wave
            // (yy % 8 == wv) but DMA rows by ((gy0-ymin)+wv+8k); when
            // -ymin % 8 != 0 these differ across waves, and lgkmcnt(0)
            // only orders within a wave (race observed in round 16).
            int lx0 = gx0 - xmin, lxn = gx1 - gx0;
            for (int yy = wv; yy < nyn; yy += HC) {
                float* dst = tile + __mul24(yy, PITCH);
                for (int xx = lane; xx < nxn; xx += 64) dst[xx] = 0.0f;
            }
            __syncthreads();                     // zeros visible to ALL waves
            for (int gy = gy0 + wv; gy < gy1; gy += HC) {
                int yy = gy - ymin;
                const float* __restrict__ src = img + (size_t)gy * IMG + gx0;
                float* dst = tile + (__mul24(yy, PITCH) + lx0);
                for (int k = 0; k < lxn; k += 64)
                    if (k + lane < lxn) gload_lds4(src + k + lane, dst + k);
            }
        }
        __syncthreads();                         // DMA drained (vmcnt0 + barrier)

        // 8 samples along h, 4-wide ILP batches
        float tb = (float)(st * HT + wv * HPER) - 255.5f;
        float fx = fmaf(s, tb, fmaf(c,  u, 255.5f - (float)xmin));
        float fy = fmaf(c, tb, fmaf(-s, u, 255.5f - (float)ymin));
        #pragma unroll
        for (int b = 0; b < HPER / 4; ++b) {
            float fx0 = fx,       fy0 = fy;
            float fx1 = fx0 + s,  fy1 = fy0 + c;
            float fx2 = fx1 + s,  fy2 = fy1 + c;
            float fx3 = fx2 + s,  fy3 = fy2 + c;
            fx = fx3 + s;  fy = fy3 + c;
            acc += lerp4<PITCH>(tile, fx0, fy0);
            acc += lerp4<PITCH>(tile, fx1, fy1);
            acc += lerp4<PITCH>(tile, fx2, fy2);
            acc += lerp4<PITCH>(tile, fx3, fy3);
        }
    }

    // reduce 8 wave-partials per w; each output written exactly once
    __syncthreads();
    tile[threadIdx.x] = acc;
    __syncthreads();
    if (threadIdx.x < WT) {
        float r = 0.0f;
        #pragma unroll
        for (int k = 0; k < HC; ++k) r += tile[k * WT + threadIdx.x];
        out[((size_t)n * IMG + w0 + threadIdx.x) * A + a] = r;
    }
}

__global__ __launch_bounds__(NT, 8) void radon_lds(
    const float* __restrict__ x, const float* __restrict__ theta,
    float* __restrict__ out, int N, int A)
{
    __shared__ float tile[BUF_FLOATS];
    int a  = blockIdx.z % A;
    int n  = blockIdx.z / A;
    int w0 = blockIdx.x * WT;

    float rad = theta[a] * 0.017453292519943295f;
    float s, c;
    __sincosf(rad, &s, &c);            // theta in [0,179] deg -> s >= 0

    const float* __restrict__ img = x + (size_t)n * (IMG * IMG);
    if (c * s >= 0.0f)
        radon_body<PITCH_A>(img, tile, out, s, c, n, a, w0, A);
    else
        radon_body<PITCH_B>(img, tile, out, s, c, n, a, w0, A);
}

extern "C" void kernel_launch(void* const* d_in, const int* in_sizes, int n_in,
                              void* d_out, int out_size, void* d_ws, size_t ws_size,
                              hipStream_t stream) {
    const float* x     = (const float*)d_in[0];
    const float* theta = (const float*)d_in[1];
    float* out = (float*)d_out;

    int A = in_sizes[1];                   // 180
    int N = in_sizes[0] / (IMG * IMG);     // 2

    dim3 grid(IMG / WT, 1, N * A);         // 8 x 1 x 360 = 2880 WGs
    radon_lds<<<grid, NT, 0, stream>>>(x, theta, out, N, A);
}